// Round 8
// baseline (20468.831 us; speedup 1.0000x reference)
//
#include <hip/hip_runtime.h>

typedef _Float16 f16;
typedef _Float16 f16x4v __attribute__((ext_vector_type(4)));
typedef _Float16 f16x8  __attribute__((ext_vector_type(8)));
typedef float    f32x4  __attribute__((ext_vector_type(4)));
typedef unsigned long long u64;
typedef unsigned int u32;

#define NB 32
#define NT 512
#define NF 512
#define NH 512
#define NG 2048   // 4*NH gate columns

// workspace layout (bytes)
static const size_t XH_OFF   = 0;
static const size_t XH_BYTES = (size_t)NB*NT*NF*2;        // 16 MiB fp16 x (DEAD after k_gx -> variant scratch)
static const size_t WT_OFF   = XH_OFF + XH_BYTES;
static const size_t WT_BYTES = (size_t)2*NG*1024*2;       //  8 MiB Wt[dir][col][k] fp16
static const size_t GX_OFF   = WT_OFF + WT_BYTES;
static const size_t GX_BYTES = (size_t)2*NT*65536*2;      // 128 MiB gxp[dir][slot][rank][wv][lane][32]
static const size_t HB_OFF   = GX_OFF + GX_BYTES;
static const size_t HB_BYTES = (size_t)2*2*NB*NH*2;       // 128 KiB h exchange [slot][dir][b][k]

__device__ __forceinline__ float sigf(float x){ return 1.0f/(1.0f+__expf(-x)); }
__device__ __forceinline__ float tanh_f(float x){ return 1.0f - 2.0f/(__expf(2.0f*x)+1.0f); }

__global__ void k_zero(float4* o, size_t no, uint4* z, size_t nz) {
  size_t i = (size_t)blockIdx.x*blockDim.x + threadIdx.x;
  size_t st = (size_t)gridDim.x*blockDim.x;
  float4 fz = make_float4(0.f,0.f,0.f,0.f);
  uint4  uz = make_uint4(0u,0u,0u,0u);
  for (size_t j=i; j<no; j+=st) o[j]=fz;
  for (size_t j=i; j<nz; j+=st) z[j]=uz;
}

__global__ void k_cvt(const float* __restrict__ x, f16* __restrict__ xh) {
  size_t i = ((size_t)blockIdx.x*blockDim.x + threadIdx.x)*4;
  float4 v = *(const float4*)(x+i);
  f16x4v h; h[0]=(f16)v.x; h[1]=(f16)v.y; h[2]=(f16)v.z; h[3]=(f16)v.w;
  *(f16x4v*)(xh+i) = h;
}

// W [1024][2048] f32 -> Wt[dir][col 2048][k 1024] fp16 (tiled transpose)
__global__ void k_tw(const float* __restrict__ Wfw, const float* __restrict__ Wbw,
                     f16* __restrict__ Wt) {
  __shared__ f16 tile[32][33];
  int b = blockIdx.x;
  int dir = b >> 11; int rem = b & 2047;
  int kt = rem >> 6, ct = rem & 63;
  const float* W = dir ? Wbw : Wfw;
  int tx = threadIdx.x & 31, ty0 = threadIdx.x >> 5;
  int k0 = kt*32, c0 = ct*32;
  for (int yy=ty0; yy<32; yy+=8)
    tile[yy][tx] = (f16)W[(size_t)(k0+yy)*2048 + c0 + tx];
  __syncthreads();
  f16* Wd = Wt + (size_t)dir*2048*1024;
  for (int yy=ty0; yy<32; yy+=8)
    Wd[(size_t)(c0+yy)*1024 + k0 + tx] = tile[tx][yy];
}

// gxp = x@Wx + bias in consumer-lane-fragment order; bw time reversal folded into slot.
__global__ __launch_bounds__(256) void k_gx(const f16* __restrict__ xh,
    const f16* __restrict__ Wt, const float* __restrict__ bfw,
    const float* __restrict__ bbw, const int* __restrict__ seqlen,
    f16* __restrict__ gxp)
{
  __shared__ f16 As[128*32];
  __shared__ f16 Bs[128*32];
  int bm0 = blockIdx.x * 128;
  int bn0 = blockIdx.y * 128;
  int dir = blockIdx.z;
  const f16* Wd = Wt + (size_t)dir*NG*1024;
  const float* bias = dir ? bbw : bfw;

  int tid = threadIdx.x;
  int w = tid>>6, lane = tid&63;
  int cc = lane&15, q = lane>>4;
  int wm = w>>1, wn = w&1;

  f32x4 acc[4][4];
#pragma unroll
  for (int i=0;i<4;++i)
#pragma unroll
    for (int j=0;j<4;++j) acc[i][j] = (f32x4){0.f,0.f,0.f,0.f};

  for (int kt=0; kt<16; ++kt) {
    int k0 = kt*32;
#pragma unroll
    for (int c=0;c<2;++c) {
      int ch = w*2 + c;
      int row = ch*16 + (lane>>2);
      int cph = (lane&3)*16;
      int clg = cph ^ (((row>>1)&3)<<4);
      const f16* ga = xh + (size_t)(bm0+row)*NF   + k0 + (clg>>1);
      const f16* gb = Wd + (size_t)(bn0+row)*1024 + k0 + (clg>>1);
      __builtin_amdgcn_global_load_lds(
          (const __attribute__((address_space(1))) u32*)ga,
          (__attribute__((address_space(3))) u32*)(As + ch*512), 16, 0, 0);
      __builtin_amdgcn_global_load_lds(
          (const __attribute__((address_space(1))) u32*)gb,
          (__attribute__((address_space(3))) u32*)(Bs + ch*512), 16, 0, 0);
    }
    __syncthreads();

    f16x8 av[4], bv[4];
#pragma unroll
    for (int mi=0;mi<4;++mi) {
      int r = wm*64 + mi*16 + cc;
      int sw = ((r>>1)&3)<<4;
      u64 lo = *(const u64*)&As[r*32 + ((((q*8)   ) ^ sw)>>1)];
      u64 hi = *(const u64*)&As[r*32 + ((((q*8)+32) ^ sw)>>1)];
      f16x4v l4 = __builtin_bit_cast(f16x4v, lo);
      f16x4v h4 = __builtin_bit_cast(f16x4v, hi);
      f16x8 a; a[0]=l4[0];a[1]=l4[1];a[2]=l4[2];a[3]=l4[3];
      a[4]=h4[0];a[5]=h4[1];a[6]=h4[2];a[7]=h4[3];
      av[mi]=a;
    }
#pragma unroll
    for (int ni=0;ni<4;++ni) {
      int r = wn*64 + ni*16 + cc;
      int sw = ((r>>1)&3)<<4;
      u64 lo = *(const u64*)&Bs[r*32 + ((((q*8)   ) ^ sw)>>1)];
      u64 hi = *(const u64*)&Bs[r*32 + ((((q*8)+32) ^ sw)>>1)];
      f16x4v l4 = __builtin_bit_cast(f16x4v, lo);
      f16x4v h4 = __builtin_bit_cast(f16x4v, hi);
      f16x8 a; a[0]=l4[0];a[1]=l4[1];a[2]=l4[2];a[3]=l4[3];
      a[4]=h4[0];a[5]=h4[1];a[6]=h4[2];a[7]=h4[3];
      bv[ni]=a;
    }
#pragma unroll
    for (int mi=0;mi<4;++mi)
#pragma unroll
      for (int ni=0;ni<4;++ni)
        acc[mi][ni] = __builtin_amdgcn_mfma_f32_16x16x32_f16(av[mi], bv[ni], acc[mi][ni], 0,0,0);
    __syncthreads();
  }

  int b = bm0 >> 9;
  int L = seqlen[b];
  int boff  = (b>>4)*4 + (b&3);
  int blane = ((b>>2)&3)*16;
  f16* gd = gxp + (size_t)dir*NT*65536;
#pragma unroll
  for (int ni=0;ni<4;++ni) {
    int col = bn0 + wn*64 + ni*16 + cc;
    int g = col>>9, n = col&511;
    int rk = n>>6, wv = (n>>4)&3, ccc = n&15;
    float bvl = bias[col];
    size_t coff = (size_t)(((rk*4 + wv)*64 + blane + ccc)*32 + g*8 + boff);
#pragma unroll
    for (int mi=0;mi<4;++mi)
#pragma unroll
      for (int rr=0;rr<4;++rr) {
        int t = (bm0&511) + wm*64 + mi*16 + q*4 + rr;
        int slot = dir ? ((t < L) ? (L-1-t) : t) : t;
        gd[(size_t)slot*65536 + coff] = (f16)(acc[mi][ni][rr] + bvl);
      }
  }
}

// Persistent recurrence, zero-sync tag-in-data (R7 structure), templated for
// ablation:
//   MODE 0: real kernel (identical logic to R7).
//   MODE 1: NO poll (h loaded unconditionally) -> local work incl. h-load latency.
//   MODE 2: NO h section at all (MFMA operands from gx regs) -> compute+gx+store floor.
//   MODE 3: poll + tagged publish ONLY (no MFMA/act/gx/out) -> raw sync-chain RTT.
// Variants write out to dead scratch via omask; only MODE 0 writes d_out.
template<int MODE>
__global__ __launch_bounds__(256, 1) __attribute__((amdgpu_waves_per_eu(1, 1)))
void k_rnn_t(const f16* __restrict__ gxp, const f16* __restrict__ Wt,
             u64* hbuf, const int* __restrict__ seqlen,
             float* __restrict__ out, u32 omask)
{
  constexpr bool HSEC = (MODE==0)||(MODE==1)||(MODE==3);
  constexpr bool POLL = (MODE==0)||(MODE==3);
  constexpr bool COMP = (MODE!=3);

  int bid = blockIdx.x;
  int dir = bid >> 3, rank = bid & 7;
  int tid = threadIdx.x;
  int w = tid>>6, lane = tid&63, cc = lane&15, q = lane>>4;
  int ncol0 = rank*64 + w*16;

  f16x8 Wf[16][4];
  if constexpr (COMP) {
    const f16* Wd = Wt + (size_t)dir*NG*1024;
#pragma unroll
    for (int kk=0;kk<16;++kk)
#pragma unroll
      for (int g=0;g<4;++g) {
        const f16* pp = Wd + (size_t)(g*NH + ncol0 + cc)*1024 + 512 + kk*32 + q*4;
        f16x4v lo = *(const f16x4v*)pp;
        f16x4v hi = *(const f16x4v*)(pp+16);
        f16x8 a; a[0]=lo[0];a[1]=lo[1];a[2]=lo[2];a[3]=lo[3];
        a[4]=hi[0];a[5]=hi[1];a[6]=hi[2];a[7]=hi[3];
        Wf[kk][g] = a;
      }
  }

  int Lr[2][4];
#pragma unroll
  for (int mi=0;mi<2;++mi)
#pragma unroll
    for (int rr=0;rr<4;++rr)
      Lr[mi][rr] = seqlen[mi*16 + q*4 + rr];

  float cst[2][4], hst[2][4];
#pragma unroll
  for (int mi=0;mi<2;++mi)
#pragma unroll
    for (int rr=0;rr<4;++rr) { cst[mi][rr]=0.f; hst[mi][rr]=0.f; }

  const f16* gwave = gxp + ((size_t)(((dir*NT)*8 + rank)*4 + w))*2048 + (size_t)lane*32;

  for (int s = 0; s < NT; ++s) {
    int slot_r = s & 1, slot_w = (s+1) & 1;
    u64 tg_r = (u64)(((s+1)>>1) & 1);
    u32 tg_w = (u32)(((s+2)>>1) & 1);

    uint4 g0, g1, g2, g3;
    if constexpr (MODE != 3) {
      const uint4* gp = (const uint4*)(gwave + (size_t)s*65536);
      g0 = gp[0]; g1 = gp[1]; g2 = gp[2]; g3 = gp[3];
    }

    f32x4 acc[4][2];
#pragma unroll
    for (int g=0;g<4;++g)
#pragma unroll
      for (int mi=0;mi<2;++mi) acc[g][mi] = (f32x4){0.f,0.f,0.f,0.f};

    if (s > 0) {
      if constexpr (HSEC) {
        const u64* hb = hbuf + (size_t)(slot_r*2+dir)*NB*(NH/4);
        const u64* pb0 = hb + (size_t)cc*(NH/4) + q;
        const u64* pb1 = hb + (size_t)(16+cc)*(NH/4) + q;
        u64 vb[8][4];
#pragma unroll
        for (int kk=0;kk<8;++kk) {
          vb[kk][0] = __hip_atomic_load(pb0 + kk*8,     __ATOMIC_RELAXED, __HIP_MEMORY_SCOPE_AGENT);
          vb[kk][1] = __hip_atomic_load(pb0 + kk*8 + 4, __ATOMIC_RELAXED, __HIP_MEMORY_SCOPE_AGENT);
          vb[kk][2] = __hip_atomic_load(pb1 + kk*8,     __ATOMIC_RELAXED, __HIP_MEMORY_SCOPE_AGENT);
          vb[kk][3] = __hip_atomic_load(pb1 + kk*8 + 4, __ATOMIC_RELAXED, __HIP_MEMORY_SCOPE_AGENT);
        }
#pragma unroll
        for (int kk=0;kk<16;++kk) {
          int sl = kk & 7;
          u64 a0 = vb[sl][0], a1 = vb[sl][1], a2 = vb[sl][2], a3 = vb[sl][3];
          if constexpr (POLL) {
            for (;;) {
              u64 bad = ((a0 ^ tg_r) | (a1 ^ tg_r) | (a2 ^ tg_r) | (a3 ^ tg_r)) & 1ull;
              if (__all(bad == 0)) break;
              a0 = __hip_atomic_load(pb0 + kk*8,     __ATOMIC_RELAXED, __HIP_MEMORY_SCOPE_AGENT);
              a1 = __hip_atomic_load(pb0 + kk*8 + 4, __ATOMIC_RELAXED, __HIP_MEMORY_SCOPE_AGENT);
              a2 = __hip_atomic_load(pb1 + kk*8,     __ATOMIC_RELAXED, __HIP_MEMORY_SCOPE_AGENT);
              a3 = __hip_atomic_load(pb1 + kk*8 + 4, __ATOMIC_RELAXED, __HIP_MEMORY_SCOPE_AGENT);
            }
          }
          if constexpr (MODE != 3) {
            f16x4v l0 = __builtin_bit_cast(f16x4v, a0), h0 = __builtin_bit_cast(f16x4v, a1);
            f16x4v l1 = __builtin_bit_cast(f16x4v, a2), h1 = __builtin_bit_cast(f16x4v, a3);
            f16x8 af0, af1;
            af0[0]=l0[0];af0[1]=l0[1];af0[2]=l0[2];af0[3]=l0[3];
            af0[4]=h0[0];af0[5]=h0[1];af0[6]=h0[2];af0[7]=h0[3];
            af1[0]=l1[0];af1[1]=l1[1];af1[2]=l1[2];af1[3]=l1[3];
            af1[4]=h1[0];af1[5]=h1[1];af1[6]=h1[2];af1[7]=h1[3];
#pragma unroll
            for (int g=0;g<4;++g) {
              acc[g][0] = __builtin_amdgcn_mfma_f32_16x16x32_f16(af0, Wf[kk][g], acc[g][0], 0,0,0);
              acc[g][1] = __builtin_amdgcn_mfma_f32_16x16x32_f16(af1, Wf[kk][g], acc[g][1], 0,0,0);
            }
          } else {
            // keep polled values live without compute
            asm volatile("" :: "v"(a0), "v"(a1), "v"(a2), "v"(a3));
          }
          if (kk < 8) {
            int kn = kk + 8;
            vb[sl][0] = __hip_atomic_load(pb0 + kn*8,     __ATOMIC_RELAXED, __HIP_MEMORY_SCOPE_AGENT);
            vb[sl][1] = __hip_atomic_load(pb0 + kn*8 + 4, __ATOMIC_RELAXED, __HIP_MEMORY_SCOPE_AGENT);
            vb[sl][2] = __hip_atomic_load(pb1 + kn*8,     __ATOMIC_RELAXED, __HIP_MEMORY_SCOPE_AGENT);
            vb[sl][3] = __hip_atomic_load(pb1 + kn*8 + 4, __ATOMIC_RELAXED, __HIP_MEMORY_SCOPE_AGENT);
          }
        }
      } else {  // MODE 2: MFMAs fed from step-dependent gx regs (no h anywhere)
        f16x8 af0 = __builtin_bit_cast(f16x8, g0);
        f16x8 af1 = __builtin_bit_cast(f16x8, g1);
#pragma unroll
        for (int kk=0;kk<16;++kk)
#pragma unroll
          for (int g=0;g<4;++g) {
            acc[g][0] = __builtin_amdgcn_mfma_f32_16x16x32_f16(af0, Wf[kk][g], acc[g][0], 0,0,0);
            acc[g][1] = __builtin_amdgcn_mfma_f32_16x16x32_f16(af1, Wf[kk][g], acc[g][1], 0,0,0);
          }
      }
    }

    float hnv[2][4];
    if constexpr (COMP) {
      f16x8 c0 = __builtin_bit_cast(f16x8, g0);
      f16x8 c1 = __builtin_bit_cast(f16x8, g1);
      f16x8 c2 = __builtin_bit_cast(f16x8, g2);
      f16x8 c3 = __builtin_bit_cast(f16x8, g3);
#pragma unroll
      for (int mi=0;mi<2;++mi)
#pragma unroll
        for (int rr=0;rr<4;++rr) {
          float gi = acc[0][mi][rr] + (float)c0[mi*4+rr];
          float gj = acc[1][mi][rr] + (float)c1[mi*4+rr];
          float gf = acc[2][mi][rr] + (float)c2[mi*4+rr];
          float go = acc[3][mi][rr] + (float)c3[mi*4+rr];
          float hv = hst[mi][rr];
          if (s < Lr[mi][rr]) {
            float cn = sigf(gf + 1.0f)*cst[mi][rr] + sigf(gi)*tanh_f(gj);
            float hn = sigf(go)*tanh_f(cn);
            cst[mi][rr] = cn; hst[mi][rr] = hn; hv = hn;
          }
          hnv[mi][rr] = hv;
        }
    } else {
#pragma unroll
      for (int mi=0;mi<2;++mi)
#pragma unroll
        for (int rr=0;rr<4;++rr) hnv[mi][rr] = 0.f;
    }

    // tagged h publish (all modes — the chain's write side)
    u64* hw = hbuf + (size_t)(slot_w*2+dir)*NB*(NH/4);
#pragma unroll
    for (int mi=0;mi<2;++mi)
#pragma unroll
      for (int rr=0;rr<4;++rr) {
        f16 hf = (f16)hnv[mi][rr];
        u32 hb16 = (u32)__builtin_bit_cast(unsigned short, hf);
        if ((cc & 3) == 0) hb16 = (hb16 & 0xFFFEu) | tg_w;
        u32 nb = (u32)__shfl_down((int)hb16, 1);
        u32 pk = hb16 | (nb << 16);
        u32 pk2 = (u32)__shfl_down((int)pk, 2);
        if ((cc & 3) == 0) {
          u64 val = (u64)pk | ((u64)pk2 << 32);
          int b = mi*16 + q*4 + rr;
          __hip_atomic_store(hw + (size_t)b*(NH/4) + ((ncol0+cc)>>2), val,
                             __ATOMIC_RELAXED, __HIP_MEMORY_SCOPE_AGENT);
        }
      }

    if constexpr (MODE == 0) {
#pragma unroll
      for (int mi=0;mi<2;++mi)
#pragma unroll
        for (int rr=0;rr<4;++rr) {
          int L = Lr[mi][rr];
          if (s < L) {
            int b = mi*16 + q*4 + rr;
            int u = (dir==0) ? s : (L-1-s);
            out[((size_t)b*NT + u)*(2*NH) + (size_t)dir*NH + ncol0 + cc] = hnv[mi][rr];
          }
        }
    } else if constexpr (MODE == 1 || MODE == 2) {
#pragma unroll
      for (int mi=0;mi<2;++mi)
#pragma unroll
        for (int rr=0;rr<4;++rr) {
          int L = Lr[mi][rr];
          if (s < L) {
            int b = mi*16 + q*4 + rr;
            int u = (dir==0) ? s : (L-1-s);
            size_t oi = ((size_t)b*NT + u)*(2*NH) + (size_t)dir*NH + ncol0 + cc;
            out[oi & (size_t)omask] = hnv[mi][rr];
          }
        }
    }
  }
}

extern "C" void kernel_launch(void* const* d_in, const int* in_sizes, int n_in,
                              void* d_out, int out_size, void* d_ws, size_t ws_size,
                              hipStream_t stream) {
  (void)in_sizes; (void)n_in; (void)out_size; (void)ws_size;
  const float* x      = (const float*)d_in[0];
  const int*   seqlen = (const int*)  d_in[1];
  const float* Wfw    = (const float*)d_in[2];
  const float* bfw    = (const float*)d_in[3];
  const float* Wbw    = (const float*)d_in[4];
  const float* bbw    = (const float*)d_in[5];
  float* out = (float*)d_out;
  unsigned char* ws = (unsigned char*)d_ws;

  f16* xh   = (f16*)(ws + XH_OFF);
  f16* Wt   = (f16*)(ws + WT_OFF);
  f16* gxp  = (f16*)(ws + GX_OFF);
  u64* hbuf = (u64*)(ws + HB_OFF);

  size_t no = (size_t)NB*NT*2*NH/4;            // float4 count of d_out
  size_t nz = HB_BYTES/16;                     // uint4 count of hbuf
  k_zero<<<dim3(2048), dim3(256), 0, stream>>>((float4*)d_out, no,
                                               (uint4*)(ws + HB_OFF), nz);
  k_cvt<<<dim3((NB*NT*NF/4)/256), dim3(256), 0, stream>>>(x, xh);
  k_tw <<<dim3(4096), dim3(256), 0, stream>>>(Wfw, Wbw, Wt);
  k_gx <<<dim3(128, 16, 2), dim3(256), 0, stream>>>(xh, Wt, bfw, bbw, seqlen, gxp);

  // real kernel
  k_rnn_t<0><<<dim3(16), dim3(256), 0, stream>>>(gxp, Wt, hbuf, seqlen, out, 0xFFFFFFFFu);

  // diagnostic ablations (write only to dead xh scratch; read-only elsewhere)
  float* oscr = (float*)(ws + XH_OFF);
  u32 om = (u32)(XH_BYTES/sizeof(float) - 1);
  k_rnn_t<1><<<dim3(16), dim3(256), 0, stream>>>(gxp, Wt, hbuf, seqlen, oscr, om);
  k_rnn_t<2><<<dim3(16), dim3(256), 0, stream>>>(gxp, Wt, hbuf, seqlen, oscr, om);
  k_rnn_t<3><<<dim3(16), dim3(256), 0, stream>>>(gxp, Wt, hbuf, seqlen, oscr, om);
}

// Round 10
// 3832.882 us; speedup vs baseline: 5.3403x; 5.3403x over previous
//
#include <hip/hip_runtime.h>

typedef _Float16 f16;
typedef _Float16 f16x4v __attribute__((ext_vector_type(4)));
typedef _Float16 f16x8  __attribute__((ext_vector_type(8)));
typedef float    f32x4  __attribute__((ext_vector_type(4)));
typedef unsigned long long u64;
typedef unsigned int u32;

#define NB 32
#define NT 512
#define NF 512
#define NH 512
#define NG 2048   // 4*NH gate columns

// workspace layout (bytes)
static const size_t XH_OFF   = 0;
static const size_t XH_BYTES = (size_t)NB*NT*NF*2;        // 16 MiB fp16 x
static const size_t WT_OFF   = XH_OFF + XH_BYTES;
static const size_t WT_BYTES = (size_t)2*NG*1024*2;       //  8 MiB Wt[dir][col][k] fp16
static const size_t GX_OFF   = WT_OFF + WT_BYTES;
static const size_t GX_BYTES = (size_t)2*NT*65536*2;      // 128 MiB gxp[dir*NT+slot][rank][grp][tt][gate][2]
static const size_t HB_OFF   = GX_OFF + GX_BYTES;
static const size_t HB_BYTES = (size_t)2*2*2*16*128*8;    // 128 KiB hbuf[grp][par][dir][b16][ko128] u64

__device__ __forceinline__ float sigf(float x){ return 1.0f/(1.0f+__expf(-x)); }
__device__ __forceinline__ float tanh_f(float x){ return 1.0f - 2.0f/(__expf(2.0f*x)+1.0f); }

// raw barrier: LDS-ordering only; VMEM (stores/prefetches) stay in flight.
__device__ __forceinline__ void barrier_lgkm() {
  asm volatile("s_waitcnt lgkmcnt(0)" ::: "memory");
  __builtin_amdgcn_sched_barrier(0);
  __builtin_amdgcn_s_barrier();
  __builtin_amdgcn_sched_barrier(0);
  asm volatile("" ::: "memory");
}

__global__ void k_zero(float4* o, size_t no, uint4* z, size_t nz) {
  size_t i = (size_t)blockIdx.x*blockDim.x + threadIdx.x;
  size_t st = (size_t)gridDim.x*blockDim.x;
  float4 fz = make_float4(0.f,0.f,0.f,0.f);
  uint4  uz = make_uint4(0u,0u,0u,0u);
  for (size_t j=i; j<no; j+=st) o[j]=fz;
  for (size_t j=i; j<nz; j+=st) z[j]=uz;
}

__global__ void k_cvt(const float* __restrict__ x, f16* __restrict__ xh) {
  size_t i = ((size_t)blockIdx.x*blockDim.x + threadIdx.x)*4;
  float4 v = *(const float4*)(x+i);
  f16x4v h; h[0]=(f16)v.x; h[1]=(f16)v.y; h[2]=(f16)v.z; h[3]=(f16)v.w;
  *(f16x4v*)(xh+i) = h;
}

// W [1024][2048] f32 -> Wt[dir][col 2048][k 1024] fp16 (tiled transpose)
__global__ void k_tw(const float* __restrict__ Wfw, const float* __restrict__ Wbw,
                     f16* __restrict__ Wt) {
  __shared__ f16 tile[32][33];
  int b = blockIdx.x;
  int dir = b >> 11; int rem = b & 2047;
  int kt = rem >> 6, ct = rem & 63;
  const float* W = dir ? Wbw : Wfw;
  int tx = threadIdx.x & 31, ty0 = threadIdx.x >> 5;
  int k0 = kt*32, c0 = ct*32;
  for (int yy=ty0; yy<32; yy+=8)
    tile[yy][tx] = (f16)W[(size_t)(k0+yy)*2048 + c0 + tx];
  __syncthreads();
  f16* Wd = Wt + (size_t)dir*2048*1024;
  for (int yy=ty0; yy<32; yy+=8)
    Wd[(size_t)(c0+yy)*1024 + k0 + tx] = tile[tx][yy];
}

// gxp = x@Wx + bias, laid out for the act-phase consumer:
// [dir*NT+slot][rank][grp][tt 512][gate 4][inner 2]; bw time reversal in slot.
__global__ __launch_bounds__(256) void k_gx(const f16* __restrict__ xh,
    const f16* __restrict__ Wt, const float* __restrict__ bfw,
    const float* __restrict__ bbw, const int* __restrict__ seqlen,
    f16* __restrict__ gxp)
{
  __shared__ f16 As[128*32];
  __shared__ f16 Bs[128*32];
  int bm0 = blockIdx.x * 128;
  int bn0 = blockIdx.y * 128;
  int dir = blockIdx.z;
  const f16* Wd = Wt + (size_t)dir*NG*1024;
  const float* bias = dir ? bbw : bfw;

  int tid = threadIdx.x;
  int w = tid>>6, lane = tid&63;
  int cc = lane&15, q = lane>>4;
  int wm = w>>1, wn = w&1;

  f32x4 acc[4][4];
#pragma unroll
  for (int i=0;i<4;++i)
#pragma unroll
    for (int j=0;j<4;++j) acc[i][j] = (f32x4){0.f,0.f,0.f,0.f};

  for (int kt=0; kt<16; ++kt) {
    int k0 = kt*32;
#pragma unroll
    for (int c=0;c<2;++c) {
      int ch = w*2 + c;
      int row = ch*16 + (lane>>2);
      int cph = (lane&3)*16;
      int clg = cph ^ (((row>>1)&3)<<4);
      const f16* ga = xh + (size_t)(bm0+row)*NF   + k0 + (clg>>1);
      const f16* gb = Wd + (size_t)(bn0+row)*1024 + k0 + (clg>>1);
      __builtin_amdgcn_global_load_lds(
          (const __attribute__((address_space(1))) u32*)ga,
          (__attribute__((address_space(3))) u32*)(As + ch*512), 16, 0, 0);
      __builtin_amdgcn_global_load_lds(
          (const __attribute__((address_space(1))) u32*)gb,
          (__attribute__((address_space(3))) u32*)(Bs + ch*512), 16, 0, 0);
    }
    __syncthreads();

    f16x8 av[4], bv[4];
#pragma unroll
    for (int mi=0;mi<4;++mi) {
      int r = wm*64 + mi*16 + cc;
      int sw = ((r>>1)&3)<<4;
      u64 lo = *(const u64*)&As[r*32 + ((((q*8)   ) ^ sw)>>1)];
      u64 hi = *(const u64*)&As[r*32 + ((((q*8)+32) ^ sw)>>1)];
      f16x4v l4 = __builtin_bit_cast(f16x4v, lo);
      f16x4v h4 = __builtin_bit_cast(f16x4v, hi);
      f16x8 a; a[0]=l4[0];a[1]=l4[1];a[2]=l4[2];a[3]=l4[3];
      a[4]=h4[0];a[5]=h4[1];a[6]=h4[2];a[7]=h4[3];
      av[mi]=a;
    }
#pragma unroll
    for (int ni=0;ni<4;++ni) {
      int r = wn*64 + ni*16 + cc;
      int sw = ((r>>1)&3)<<4;
      u64 lo = *(const u64*)&Bs[r*32 + ((((q*8)   ) ^ sw)>>1)];
      u64 hi = *(const u64*)&Bs[r*32 + ((((q*8)+32) ^ sw)>>1)];
      f16x4v l4 = __builtin_bit_cast(f16x4v, lo);
      f16x4v h4 = __builtin_bit_cast(f16x4v, hi);
      f16x8 a; a[0]=l4[0];a[1]=l4[1];a[2]=l4[2];a[3]=l4[3];
      a[4]=h4[0];a[5]=h4[1];a[6]=h4[2];a[7]=h4[3];
      bv[ni]=a;
    }
#pragma unroll
    for (int mi=0;mi<4;++mi)
#pragma unroll
      for (int ni=0;ni<4;++ni)
        acc[mi][ni] = __builtin_amdgcn_mfma_f32_16x16x32_f16(av[mi], bv[ni], acc[mi][ni], 0,0,0);
    __syncthreads();
  }

  // epilogue: scatter into consumer layout
  int b = bm0 >> 9;
  int L = seqlen[b];
  int grp = b >> 4, bl = b & 15;
#pragma unroll
  for (int ni=0;ni<4;++ni) {
    int col = bn0 + wn*64 + ni*16 + cc;
    int gate = col >> 9, n = col & 511;
    int rk = n >> 6, c_l = n & 63;
    int idx = bl*64 + c_l;
    int tt = idx >> 1, inner = idx & 1;
    float bvl = bias[col];
    size_t coff = ((((size_t)rk*2 + grp)*512 + tt)*4 + gate)*2 + inner;
#pragma unroll
    for (int mi=0;mi<4;++mi)
#pragma unroll
      for (int rr=0;rr<4;++rr) {
        int t = (bm0&511) + wm*64 + mi*16 + q*4 + rr;
        int slot = dir ? ((t < L) ? (L-1-t) : t) : t;
        gxp[(size_t)(dir*NT + slot)*65536 + coff] = (f16)(acc[mi][ni][rr] + bvl);
      }
  }
}

// Persistent recurrence: 16 blocks x 512 threads (8 waves), 2-group pipeline.
// Wave w: gate gg=w>>1, col-half ch=w&1 -> Wf[16][2] = 128 VGPRs (resident).
// Tag-in-data ping-pong (R7 protocol, proven): tag=((s+1)>>1)&1 in LSB of each
// u64; candidates for s+1 issued at end of step s, checked one iteration later.
// Raw s_barrier + lgkmcnt(0): no vmcnt drains anywhere in the loop.
__global__ __launch_bounds__(512, 2)
void k_rnn(const f16* __restrict__ gxp, const f16* __restrict__ Wt,
           u64* hbuf, const int* __restrict__ seqlen, float* __restrict__ out)
{
  __shared__ u64   hstage[16*129];
  __shared__ float gacc[4*64*20];
  __shared__ f16   htile[16*72];

  int bid = blockIdx.x;
  int dir = bid >> 3, rank = bid & 7;
  int tid = threadIdx.x;
  int w = tid>>6, lane = tid&63, cc = lane&15, q = lane>>4;
  int gg = w >> 1, ch = w & 1;
  int ncol0 = rank*64;
  int cb = (tid>>5)*128 + (tid&31)*4;     // my 4 candidate u64s
  int pb = tid>>4, pq = tid&15;           // publisher mapping (tid<256)

  // Persistent W_h: col = gg*512 + ncol0 + ch*32 + f*16 + cc; k = 512 + kk*32 + q*4 (+16)
  f16x8 Wf[16][2];
  {
    const f16* Wd = Wt + (size_t)dir*NG*1024;
#pragma unroll
    for (int kk=0;kk<16;++kk)
#pragma unroll
      for (int f=0;f<2;++f) {
        const f16* pp = Wd + (size_t)(gg*NH + ncol0 + ch*32 + f*16 + cc)*1024 + 512 + kk*32 + q*4;
        f16x4v lo = *(const f16x4v*)pp;
        f16x4v hi = *(const f16x4v*)(pp+16);
        f16x8 a; a[0]=lo[0];a[1]=lo[1];a[2]=lo[2];a[3]=lo[3];
        a[4]=hi[0];a[5]=hi[1];a[6]=hi[2];a[7]=hi[3];
        Wf[kk][f] = a;
      }
  }

  // act-phase pairs: idx = 2*tid (+1): (b = idx>>6, c = idx&63)
  int b0 = (2*tid)>>6, c0 = (2*tid)&63;
  int b1 = (2*tid+1)>>6, c1 = (2*tid+1)&63;
  int La0 = seqlen[b0],      Lb0 = seqlen[b1];       // grp 0
  int La1 = seqlen[16+b0],   Lb1 = seqlen[16+b1];    // grp 1
  float csA0=0.f, csB0=0.f, hsA0=0.f, hsB0=0.f;
  float csA1=0.f, csB1=0.f, hsA1=0.f, hsB1=0.f;

  u64 cu0[4] = {0,0,0,0}, cu1[4] = {0,0,0,0};
  uint4 gxc0, gxc1;
  gxc0 = *(const uint4*)(gxp + ((size_t)(dir*NT + 0)*65536 + (((size_t)rank*2 + 0)*512 + tid)*8));
  gxc1 = *(const uint4*)(gxp + ((size_t)(dir*NT + 0)*65536 + (((size_t)rank*2 + 1)*512 + tid)*8));

#define PHASE(GRP, CU, GXC, CSA, HSA, CSB, HSB, LA, LB)                          \
  {                                                                              \
    if (s > 0) {                                                                 \
      const u64* hp_ = hbuf + ((size_t)((GRP*2 + pr)*2 + dir))*2048 + cb;        \
      int spin = 0;                                                              \
      for (;;) {                                                                 \
        u64 bad = ((CU[0]^tgr)|(CU[1]^tgr)|(CU[2]^tgr)|(CU[3]^tgr)) & 1ull;      \
        if (__all(bad == 0)) break;                                              \
        if (++spin > (1<<16)) break;                                             \
        CU[0] = __hip_atomic_load(hp_+0, __ATOMIC_RELAXED, __HIP_MEMORY_SCOPE_AGENT); \
        CU[1] = __hip_atomic_load(hp_+1, __ATOMIC_RELAXED, __HIP_MEMORY_SCOPE_AGENT); \
        CU[2] = __hip_atomic_load(hp_+2, __ATOMIC_RELAXED, __HIP_MEMORY_SCOPE_AGENT); \
        CU[3] = __hip_atomic_load(hp_+3, __ATOMIC_RELAXED, __HIP_MEMORY_SCOPE_AGENT); \
        __builtin_amdgcn_s_sleep(1);                                             \
      }                                                                          \
      { u64* hz_ = &hstage[(tid>>5)*129 + (tid&31)*4];                           \
        hz_[0]=CU[0]; hz_[1]=CU[1]; hz_[2]=CU[2]; hz_[3]=CU[3]; }                \
      barrier_lgkm();                                                            \
      f32x4 ac0 = {0.f,0.f,0.f,0.f}, ac1 = {0.f,0.f,0.f,0.f};                    \
      _Pragma("unroll")                                                          \
      for (int kk=0; kk<16; ++kk) {                                              \
        u64 alo = hstage[cc*129 + kk*8 + q];                                     \
        u64 ahi = hstage[cc*129 + kk*8 + q + 4];                                 \
        f16x4v l4_ = __builtin_bit_cast(f16x4v, alo);                            \
        f16x4v h4_ = __builtin_bit_cast(f16x4v, ahi);                            \
        f16x8 af; af[0]=l4_[0];af[1]=l4_[1];af[2]=l4_[2];af[3]=l4_[3];           \
        af[4]=h4_[0];af[5]=h4_[1];af[6]=h4_[2];af[7]=h4_[3];                     \
        ac0 = __builtin_amdgcn_mfma_f32_16x16x32_f16(af, Wf[kk][0], ac0, 0,0,0); \
        ac1 = __builtin_amdgcn_mfma_f32_16x16x32_f16(af, Wf[kk][1], ac1, 0,0,0); \
      }                                                                          \
      *(f32x4*)&gacc[(gg*64 + ch*32 + cc)*20 + q*4]      = ac0;                  \
      *(f32x4*)&gacc[(gg*64 + ch*32 + 16 + cc)*20 + q*4] = ac1;                  \
      barrier_lgkm();                                                            \
    } else {                                                                     \
      barrier_lgkm();                                                            \
    }                                                                            \
    {                                                                            \
      f16x8 gv = __builtin_bit_cast(f16x8, GXC);                                 \
      float giA,gjA,gfA,goA, giB,gjB,gfB,goB;                                    \
      if (s > 0) {                                                               \
        giA = gacc[(0*64 + c0)*20 + b0]; gjA = gacc[(1*64 + c0)*20 + b0];        \
        gfA = gacc[(2*64 + c0)*20 + b0]; goA = gacc[(3*64 + c0)*20 + b0];        \
        giB = gacc[(0*64 + c1)*20 + b1]; gjB = gacc[(1*64 + c1)*20 + b1];        \
        gfB = gacc[(2*64 + c1)*20 + b1]; goB = gacc[(3*64 + c1)*20 + b1];        \
      } else { giA=gjA=gfA=goA=giB=gjB=gfB=goB=0.f; }                            \
      giA += (float)gv[0]; gjA += (float)gv[2]; gfA += (float)gv[4]; goA += (float)gv[6]; \
      giB += (float)gv[1]; gjB += (float)gv[3]; gfB += (float)gv[5]; goB += (float)gv[7]; \
      if (s < LA) {                                                              \
        float cn = sigf(gfA + 1.0f)*CSA + sigf(giA)*tanh_f(gjA);                 \
        float hn = sigf(goA)*tanh_f(cn);                                         \
        CSA = cn; HSA = hn;                                                      \
        int u_ = dir ? (LA-1-s) : s;                                             \
        out[((size_t)(GRP*16 + b0)*NT + u_)*(2*NH) + (size_t)dir*NH + ncol0 + c0] = hn; \
      }                                                                          \
      if (s < LB) {                                                              \
        float cn = sigf(gfB + 1.0f)*CSB + sigf(giB)*tanh_f(gjB);                 \
        float hn = sigf(goB)*tanh_f(cn);                                         \
        CSB = cn; HSB = hn;                                                      \
        int u_ = dir ? (LB-1-s) : s;                                             \
        out[((size_t)(GRP*16 + b1)*NT + u_)*(2*NH) + (size_t)dir*NH + ncol0 + c1] = hn; \
      }                                                                          \
      htile[b0*72 + c0] = (f16)HSA;                                              \
      htile[b1*72 + c1] = (f16)HSB;                                              \
    }                                                                            \
    barrier_lgkm();                                                              \
    if (tid < 256) {                                                             \
      u64 hv = *(const u64*)&htile[pb*72 + pq*4];                                \
      hv = (hv & ~1ull) | (u64)tgw;                                              \
      u64* dst_ = hbuf + ((size_t)((GRP*2 + ((s+1)&1))*2 + dir))*2048 + pb*128 + rank*16 + pq; \
      __hip_atomic_store(dst_, hv, __ATOMIC_RELAXED, __HIP_MEMORY_SCOPE_AGENT);  \
    }                                                                            \
    if (s + 1 < NT) {                                                            \
      const u64* hpn_ = hbuf + ((size_t)((GRP*2 + ((s+1)&1))*2 + dir))*2048 + cb; \
      CU[0] = __hip_atomic_load(hpn_+0, __ATOMIC_RELAXED, __HIP_MEMORY_SCOPE_AGENT); \
      CU[1] = __hip_atomic_load(hpn_+1, __ATOMIC_RELAXED, __HIP_MEMORY_SCOPE_AGENT); \
      CU[2] = __hip_atomic_load(hpn_+2, __ATOMIC_RELAXED, __HIP_MEMORY_SCOPE_AGENT); \
      CU[3] = __hip_atomic_load(hpn_+3, __ATOMIC_RELAXED, __HIP_MEMORY_SCOPE_AGENT); \
      GXC = *(const uint4*)(gxp + ((size_t)(dir*NT + (s+1))*65536 + (((size_t)rank*2 + GRP)*512 + tid)*8)); \
    }                                                                            \
  }

  for (int s = 0; s < NT; ++s) {
    int pr = s & 1;
    u64 tgr = (u64)(((s+1)>>1) & 1);
    u64 tgw = (u64)(((s+2)>>1) & 1);
    PHASE(0, cu0, gxc0, csA0, hsA0, csB0, hsB0, La0, Lb0)
    PHASE(1, cu1, gxc1, csA1, hsA1, csB1, hsB1, La1, Lb1)
  }
#undef PHASE
}

extern "C" void kernel_launch(void* const* d_in, const int* in_sizes, int n_in,
                              void* d_out, int out_size, void* d_ws, size_t ws_size,
                              hipStream_t stream) {
  (void)in_sizes; (void)n_in; (void)out_size; (void)ws_size;
  const float* x      = (const float*)d_in[0];
  const int*   seqlen = (const int*)  d_in[1];
  const float* Wfw    = (const float*)d_in[2];
  const float* bfw    = (const float*)d_in[3];
  const float* Wbw    = (const float*)d_in[4];
  const float* bbw    = (const float*)d_in[5];
  float* out = (float*)d_out;
  unsigned char* ws = (unsigned char*)d_ws;

  f16* xh   = (f16*)(ws + XH_OFF);
  f16* Wt   = (f16*)(ws + WT_OFF);
  f16* gxp  = (f16*)(ws + GX_OFF);
  u64* hbuf = (u64*)(ws + HB_OFF);

  size_t no = (size_t)NB*NT*2*NH/4;            // float4 count of d_out
  size_t nz = HB_BYTES/16;                     // uint4 count of hbuf
  k_zero<<<dim3(2048), dim3(256), 0, stream>>>((float4*)d_out, no,
                                               (uint4*)(ws + HB_OFF), nz);
  k_cvt<<<dim3((NB*NT*NF/4)/256), dim3(256), 0, stream>>>(x, xh);
  k_tw <<<dim3(4096), dim3(256), 0, stream>>>(Wfw, Wbw, Wt);
  k_gx <<<dim3(128, 16, 2), dim3(256), 0, stream>>>(xh, Wt, bfw, bbw, seqlen, gxp);
  k_rnn<<<dim3(16), dim3(512), 0, stream>>>(gxp, Wt, hbuf, seqlen, out);
}

// Round 11
// 2361.308 us; speedup vs baseline: 8.6684x; 1.6232x over previous
//
#include <hip/hip_runtime.h>

typedef _Float16 f16;
typedef _Float16 f16x4v __attribute__((ext_vector_type(4)));
typedef _Float16 f16x8  __attribute__((ext_vector_type(8)));
typedef float    f32x4  __attribute__((ext_vector_type(4)));
typedef unsigned long long u64;
typedef unsigned int u32;

#define NB 32
#define NT 512
#define NF 512
#define NH 512
#define NG 2048   // 4*NH gate columns

// workspace layout (bytes)
static const size_t XH_OFF   = 0;
static const size_t XH_BYTES = (size_t)NB*NT*NF*2;        // 16 MiB fp16 x
static const size_t WT_OFF   = XH_OFF + XH_BYTES;
static const size_t WT_BYTES = (size_t)2*NG*1024*2;       //  8 MiB Wt[dir][col][k] fp16
static const size_t GX_OFF   = WT_OFF + WT_BYTES;
static const size_t GX_BYTES = (size_t)2*NT*65536*2;      // 128 MiB gxp[dir*NT+slot][rank][grp][thr256][16]
static const size_t HB_OFF   = GX_OFF + GX_BYTES;
static const size_t HB_BYTES = (size_t)2*2*2*16*128*8;    // 128 KiB hbuf[grp][par][dir][b16][ko128] u64

__device__ __forceinline__ float sigf(float x){ return 1.0f/(1.0f+__expf(-x)); }
__device__ __forceinline__ float tanh_f(float x){ return 1.0f - 2.0f/(__expf(2.0f*x)+1.0f); }

// raw barrier: LDS-ordering only; VMEM (stores/prefetches) stay in flight.
__device__ __forceinline__ void barrier_lgkm() {
  asm volatile("s_waitcnt lgkmcnt(0)" ::: "memory");
  __builtin_amdgcn_sched_barrier(0);
  __builtin_amdgcn_s_barrier();
  __builtin_amdgcn_sched_barrier(0);
  asm volatile("" ::: "memory");
}

__global__ void k_zero(float4* o, size_t no, uint4* z, size_t nz) {
  size_t i = (size_t)blockIdx.x*blockDim.x + threadIdx.x;
  size_t st = (size_t)gridDim.x*blockDim.x;
  float4 fz = make_float4(0.f,0.f,0.f,0.f);
  uint4  uz = make_uint4(0u,0u,0u,0u);
  for (size_t j=i; j<no; j+=st) o[j]=fz;
  for (size_t j=i; j<nz; j+=st) z[j]=uz;
}

__global__ void k_cvt(const float* __restrict__ x, f16* __restrict__ xh) {
  size_t i = ((size_t)blockIdx.x*blockDim.x + threadIdx.x)*4;
  float4 v = *(const float4*)(x+i);
  f16x4v h; h[0]=(f16)v.x; h[1]=(f16)v.y; h[2]=(f16)v.z; h[3]=(f16)v.w;
  *(f16x4v*)(xh+i) = h;
}

// W [1024][2048] f32 -> Wt[dir][col 2048][k 1024] fp16 (tiled transpose)
__global__ void k_tw(const float* __restrict__ Wfw, const float* __restrict__ Wbw,
                     f16* __restrict__ Wt) {
  __shared__ f16 tile[32][33];
  int b = blockIdx.x;
  int dir = b >> 11; int rem = b & 2047;
  int kt = rem >> 6, ct = rem & 63;
  const float* W = dir ? Wbw : Wfw;
  int tx = threadIdx.x & 31, ty0 = threadIdx.x >> 5;
  int k0 = kt*32, c0 = ct*32;
  for (int yy=ty0; yy<32; yy+=8)
    tile[yy][tx] = (f16)W[(size_t)(k0+yy)*2048 + c0 + tx];
  __syncthreads();
  f16* Wd = Wt + (size_t)dir*2048*1024;
  for (int yy=ty0; yy<32; yy+=8)
    Wd[(size_t)(c0+yy)*1024 + k0 + tx] = tile[tx][yy];
}

// gxp = x@Wx + bias, consumer layout:
// [dir*NT+slot][rank8][grp2][thread256 = ct*64+q*16+cc][gate4][rr4] f16
// bw time reversal folded into slot (bijection per batch).
__global__ __launch_bounds__(256) void k_gx(const f16* __restrict__ xh,
    const f16* __restrict__ Wt, const float* __restrict__ bfw,
    const float* __restrict__ bbw, const int* __restrict__ seqlen,
    f16* __restrict__ gxp)
{
  __shared__ f16 As[128*32];
  __shared__ f16 Bs[128*32];
  int bm0 = blockIdx.x * 128;
  int bn0 = blockIdx.y * 128;
  int dir = blockIdx.z;
  const f16* Wd = Wt + (size_t)dir*NG*1024;
  const float* bias = dir ? bbw : bfw;

  int tid = threadIdx.x;
  int w = tid>>6, lane = tid&63;
  int cc = lane&15, q = lane>>4;
  int wm = w>>1, wn = w&1;

  f32x4 acc[4][4];
#pragma unroll
  for (int i=0;i<4;++i)
#pragma unroll
    for (int j=0;j<4;++j) acc[i][j] = (f32x4){0.f,0.f,0.f,0.f};

  for (int kt=0; kt<16; ++kt) {
    int k0 = kt*32;
#pragma unroll
    for (int c=0;c<2;++c) {
      int ch = w*2 + c;
      int row = ch*16 + (lane>>2);
      int cph = (lane&3)*16;
      int clg = cph ^ (((row>>1)&3)<<4);
      const f16* ga = xh + (size_t)(bm0+row)*NF   + k0 + (clg>>1);
      const f16* gb = Wd + (size_t)(bn0+row)*1024 + k0 + (clg>>1);
      __builtin_amdgcn_global_load_lds(
          (const __attribute__((address_space(1))) u32*)ga,
          (__attribute__((address_space(3))) u32*)(As + ch*512), 16, 0, 0);
      __builtin_amdgcn_global_load_lds(
          (const __attribute__((address_space(1))) u32*)gb,
          (__attribute__((address_space(3))) u32*)(Bs + ch*512), 16, 0, 0);
    }
    __syncthreads();

    f16x8 av[4], bv[4];
#pragma unroll
    for (int mi=0;mi<4;++mi) {
      int r = wm*64 + mi*16 + cc;
      int sw = ((r>>1)&3)<<4;
      u64 lo = *(const u64*)&As[r*32 + ((((q*8)   ) ^ sw)>>1)];
      u64 hi = *(const u64*)&As[r*32 + ((((q*8)+32) ^ sw)>>1)];
      f16x4v l4 = __builtin_bit_cast(f16x4v, lo);
      f16x4v h4 = __builtin_bit_cast(f16x4v, hi);
      f16x8 a; a[0]=l4[0];a[1]=l4[1];a[2]=l4[2];a[3]=l4[3];
      a[4]=h4[0];a[5]=h4[1];a[6]=h4[2];a[7]=h4[3];
      av[mi]=a;
    }
#pragma unroll
    for (int ni=0;ni<4;++ni) {
      int r = wn*64 + ni*16 + cc;
      int sw = ((r>>1)&3)<<4;
      u64 lo = *(const u64*)&Bs[r*32 + ((((q*8)   ) ^ sw)>>1)];
      u64 hi = *(const u64*)&Bs[r*32 + ((((q*8)+32) ^ sw)>>1)];
      f16x4v l4 = __builtin_bit_cast(f16x4v, lo);
      f16x4v h4 = __builtin_bit_cast(f16x4v, hi);
      f16x8 a; a[0]=l4[0];a[1]=l4[1];a[2]=l4[2];a[3]=l4[3];
      a[4]=h4[0];a[5]=h4[1];a[6]=h4[2];a[7]=h4[3];
      bv[ni]=a;
    }
#pragma unroll
    for (int mi=0;mi<4;++mi)
#pragma unroll
      for (int ni=0;ni<4;++ni)
        acc[mi][ni] = __builtin_amdgcn_mfma_f32_16x16x32_f16(av[mi], bv[ni], acc[mi][ni], 0,0,0);
    __syncthreads();
  }

  // epilogue: scatter into consumer layout
  int b = bm0 >> 9;             // this block's single batch
  int L = seqlen[b];
  int grp = b >> 4, bl = b & 15;
  int q_c = bl >> 2, rr_c = bl & 3;
#pragma unroll
  for (int ni=0;ni<4;++ni) {
    int col = bn0 + wn*64 + ni*16 + cc;
    int gate = col >> 9, n = col & 511;
    int rk = n >> 6, c_l = n & 63;
    int ct_c = c_l >> 4, cc_c = c_l & 15;
    float bvl = bias[col];
    size_t coff = (size_t)((((rk*2 + grp)*256 + ct_c*64 + q_c*16 + cc_c))*16 + gate*4 + rr_c);
#pragma unroll
    for (int mi=0;mi<4;++mi)
#pragma unroll
      for (int rr=0;rr<4;++rr) {
        int t = (bm0&511) + wm*64 + mi*16 + q*4 + rr;
        int slot = dir ? ((t < L) ? (L-1-t) : t) : t;
        gxp[(size_t)(dir*NT + slot)*65536 + coff] = (f16)(acc[mi][ni][rr] + bvl);
      }
  }
}

// Persistent recurrence: 32 blocks (dir x rank x grp), 256 threads (4 waves).
// Wave ct owns cols [rank*64 + ct*16, +16) x ALL 4 gates -> all 4 gates of one
// (b,c) live in the SAME lane's accumulators: act is register-local, no gacc
// LDS, no htile. One barrier/step (double-buffered hstage). Wf = 4 gates x
// 16 kk = 256 VGPRs, pinned resident via asm. Tag-in-data ping-pong (proven):
// tag=((s+1)>>1)&1 in LSB of each u64; candidates prefetched, checked next step.
__global__ __launch_bounds__(256, 1)
void k_rnn(const f16* __restrict__ gxp, const f16* __restrict__ Wt,
           u64* hbuf, const int* __restrict__ seqlen, float* __restrict__ out)
{
  __shared__ u64 hstage[2][16*129];
  int bid = blockIdx.x;
  int dir = bid >> 4, rank = (bid >> 1) & 7, grp = bid & 1;
  int tid = threadIdx.x;
  int ct = tid >> 6, lane = tid & 63, cc = lane & 15, q = lane >> 4;
  int ncol0 = rank*64 + ct*16;

  // Persistent W_h: col = g*NH + ncol0 + cc; k = 512 + kk*32 + q*4 (+16)
  f16x8 Wf[16][4];
  {
    const f16* Wd = Wt + (size_t)dir*NG*1024;
#pragma unroll
    for (int kk=0;kk<16;++kk)
#pragma unroll
      for (int g=0;g<4;++g) {
        const f16* pp = Wd + (size_t)(g*NH + ncol0 + cc)*1024 + 512 + kk*32 + q*4;
        f16x4v lo = *(const f16x4v*)pp;
        f16x4v hi = *(const f16x4v*)(pp+16);
        f16x8 a; a[0]=lo[0];a[1]=lo[1];a[2]=lo[2];a[3]=lo[3];
        a[4]=hi[0];a[5]=hi[1];a[6]=hi[2];a[7]=hi[3];
        Wf[kk][g] = a;
      }
  }
  // pin: values become asm-opaque -> cannot be rematerialized (re-loaded) in-loop
#pragma unroll
  for (int kk=0;kk<16;++kk)
#pragma unroll
    for (int g=0;g<4;++g)
      asm volatile("" : "+v"(Wf[kk][g]));

  int Lr[4];
#pragma unroll
  for (int rr=0;rr<4;++rr) Lr[rr] = seqlen[grp*16 + q*4 + rr];

  float cst[4] = {0.f,0.f,0.f,0.f}, hst[4] = {0.f,0.f,0.f,0.f};

  int cb_b = tid >> 4;      // candidate batch 0..15
  int cb_k = tid & 15;      // candidate ko base
  u64 cu[8] = {0,0,0,0,0,0,0,0};

  uint4 gxa = *(const uint4*)(gxp + (size_t)(dir*NT + 0)*65536
                              + ((size_t)(rank*2 + grp)*256 + tid)*16);
  uint4 gxb = *(const uint4*)(gxp + (size_t)(dir*NT + 0)*65536
                              + ((size_t)(rank*2 + grp)*256 + tid)*16 + 8);

  for (int s = 0; s < NT; ++s) {
    int pr = s & 1;
    u64 tgr = (u64)(((s+1)>>1) & 1);
    u64 tgw = (u64)(((s+2)>>1) & 1);

    f32x4 acc[4];
#pragma unroll
    for (int g=0;g<4;++g) acc[g] = (f32x4){0.f,0.f,0.f,0.f};

    if (s > 0) {
      const u64* hp = hbuf + ((size_t)((grp*2 + pr)*2 + dir))*2048 + cb_b*128 + cb_k;
      int spin = 0;
      for (;;) {
        u64 bad = 0;
#pragma unroll
        for (int j=0;j<8;++j) bad |= (cu[j] ^ tgr);
        if (__all((bad & 1) == 0)) break;
        if (++spin > (1<<16)) break;   // fail loud, never hang
#pragma unroll
        for (int j=0;j<8;++j)
          cu[j] = __hip_atomic_load(hp + j*16, __ATOMIC_RELAXED, __HIP_MEMORY_SCOPE_AGENT);
        __builtin_amdgcn_s_sleep(1);
      }
      // stage to LDS (coalesced-strided: lanes stride 8B -> ~no bank conflicts)
      u64* hz = &hstage[pr][cb_b*129 + cb_k];
#pragma unroll
      for (int j=0;j<8;++j) hz[j*16] = cu[j];
      barrier_lgkm();

      const u64* hs = &hstage[pr][cc*129];
#pragma unroll
      for (int kk=0;kk<16;++kk) {
        u64 alo = hs[kk*8 + q];
        u64 ahi = hs[kk*8 + q + 4];
        f16x4v l4 = __builtin_bit_cast(f16x4v, alo);
        f16x4v h4 = __builtin_bit_cast(f16x4v, ahi);
        f16x8 af; af[0]=l4[0];af[1]=l4[1];af[2]=l4[2];af[3]=l4[3];
        af[4]=h4[0];af[5]=h4[1];af[6]=h4[2];af[7]=h4[3];
#pragma unroll
        for (int g=0;g<4;++g)
          acc[g] = __builtin_amdgcn_mfma_f32_16x16x32_f16(af, Wf[kk][g], acc[g], 0,0,0);
      }
    }

    // activations — fully register-local (all 4 gates in this lane)
    f16x8 c01 = __builtin_bit_cast(f16x8, gxa);   // gates 0,1 x rr
    f16x8 c23 = __builtin_bit_cast(f16x8, gxb);   // gates 2,3 x rr
    float hnv[4];
#pragma unroll
    for (int rr=0;rr<4;++rr) {
      float gi = acc[0][rr] + (float)c01[rr];
      float gj = acc[1][rr] + (float)c01[4+rr];
      float gf = acc[2][rr] + (float)c23[rr];
      float go = acc[3][rr] + (float)c23[4+rr];
      float hv = hst[rr];
      if (s < Lr[rr]) {
        float cn = sigf(gf + 1.0f)*cst[rr] + sigf(gi)*tanh_f(gj);
        float hn = sigf(go)*tanh_f(cn);
        cst[rr] = cn; hst[rr] = hn; hv = hn;
      }
      hnv[rr] = hv;
    }

    // out stores — fire and forget
#pragma unroll
    for (int rr=0;rr<4;++rr) {
      if (s < Lr[rr]) {
        int b = grp*16 + q*4 + rr;
        int u = dir ? (Lr[rr]-1-s) : s;
        out[((size_t)b*NT + u)*(2*NH) + (size_t)dir*NH + ncol0 + cc] = hnv[rr];
      }
    }

    // tagged publish: 2x shfl_down packs 4 cols/u64, (cc&3)==0 lanes store
    size_t wb = ((size_t)((grp*2 + ((s+1)&1))*2 + dir))*2048;
#pragma unroll
    for (int rr=0;rr<4;++rr) {
      f16 hf = (f16)hnv[rr];
      u32 v = (u32)__builtin_bit_cast(unsigned short, hf);
      if ((cc & 3) == 0) v = (v & 0xFFFEu) | (u32)tgw;
      u32 pk = v | (((u32)__shfl_down((int)v, 1)) << 16);
      u32 pk2 = (u32)__shfl_down((int)pk, 2);
      if ((cc & 3) == 0) {
        u64 val = (u64)pk | ((u64)pk2 << 32);
        int b = q*4 + rr;
        __hip_atomic_store(hbuf + wb + b*128 + rank*16 + ct*4 + (cc>>2), val,
                           __ATOMIC_RELAXED, __HIP_MEMORY_SCOPE_AGENT);
      }
    }

    // prefetch candidates + gx for s+1 (checked next iteration)
    if (s + 1 < NT) {
      const u64* hpn = hbuf + wb + cb_b*128 + cb_k;
#pragma unroll
      for (int j=0;j<8;++j)
        cu[j] = __hip_atomic_load(hpn + j*16, __ATOMIC_RELAXED, __HIP_MEMORY_SCOPE_AGENT);
      const f16* gp = gxp + (size_t)(dir*NT + (s+1))*65536
                      + ((size_t)(rank*2 + grp)*256 + tid)*16;
      gxa = *(const uint4*)gp;
      gxb = *(const uint4*)(gp + 8);
    }
  }
}

extern "C" void kernel_launch(void* const* d_in, const int* in_sizes, int n_in,
                              void* d_out, int out_size, void* d_ws, size_t ws_size,
                              hipStream_t stream) {
  (void)in_sizes; (void)n_in; (void)out_size; (void)ws_size;
  const float* x      = (const float*)d_in[0];
  const int*   seqlen = (const int*)  d_in[1];
  const float* Wfw    = (const float*)d_in[2];
  const float* bfw    = (const float*)d_in[3];
  const float* Wbw    = (const float*)d_in[4];
  const float* bbw    = (const float*)d_in[5];
  float* out = (float*)d_out;
  unsigned char* ws = (unsigned char*)d_ws;

  f16* xh   = (f16*)(ws + XH_OFF);
  f16* Wt   = (f16*)(ws + WT_OFF);
  f16* gxp  = (f16*)(ws + GX_OFF);
  u64* hbuf = (u64*)(ws + HB_OFF);

  size_t no = (size_t)NB*NT*2*NH/4;            // float4 count of d_out
  size_t nz = HB_BYTES/16;                     // uint4 count of hbuf
  k_zero<<<dim3(2048), dim3(256), 0, stream>>>((float4*)d_out, no,
                                               (uint4*)(ws + HB_OFF), nz);
  k_cvt<<<dim3((NB*NT*NF/4)/256), dim3(256), 0, stream>>>(x, xh);
  k_tw <<<dim3(4096), dim3(256), 0, stream>>>(Wfw, Wbw, Wt);
  k_gx <<<dim3(128, 16, 2), dim3(256), 0, stream>>>(xh, Wt, bfw, bbw, seqlen, gxp);
  k_rnn<<<dim3(32), dim3(256), 0, stream>>>(gxp, Wt, hbuf, seqlen, out);
}